// Round 1
// baseline (399.639 us; speedup 1.0000x reference)
//
#include <hip/hip_runtime.h>
#include <hip/hip_bf16.h>

// CosineLoss: out = 1 - mean_i( dot(a_i,b_i) / (||a_i|| * ||b_i||) )
// inputs: d_in[0] = cxr (N,D) f32, d_in[1] = ehr (N,D) f32; N=16384, D=2048.
// Memory-bound: 268 MB read -> ~43 us floor at 6.3 TB/s.

#define ROWS 16384
#define COLS 2048
#define BLOCK 256

__global__ __launch_bounds__(BLOCK) void cosine_loss_kernel(
    const float4* __restrict__ cxr,
    const float4* __restrict__ ehr,
    float* __restrict__ out) {
    const int row = blockIdx.x;
    const int nvec = COLS / 4;  // 512 float4 per row
    const float4* __restrict__ a = cxr + (size_t)row * nvec;
    const float4* __restrict__ b = ehr + (size_t)row * nvec;

    float dot = 0.f, aa = 0.f, bb = 0.f;
    // 512 vecs / 256 threads = 2 iterations, fully coalesced 16B/lane
    for (int j = threadIdx.x; j < nvec; j += BLOCK) {
        float4 x = a[j];
        float4 y = b[j];
        dot += x.x * y.x + x.y * y.y + x.z * y.z + x.w * y.w;
        aa  += x.x * x.x + x.y * x.y + x.z * x.z + x.w * x.w;
        bb  += y.x * y.x + y.y * y.y + y.z * y.z + y.w * y.w;
    }

    // wave64 butterfly reduction
    #pragma unroll
    for (int off = 32; off > 0; off >>= 1) {
        dot += __shfl_down(dot, off, 64);
        aa  += __shfl_down(aa,  off, 64);
        bb  += __shfl_down(bb,  off, 64);
    }

    __shared__ float s_dot[4], s_aa[4], s_bb[4];
    const int wave = threadIdx.x >> 6;
    const int lane = threadIdx.x & 63;
    if (lane == 0) {
        s_dot[wave] = dot;
        s_aa[wave]  = aa;
        s_bb[wave]  = bb;
    }
    __syncthreads();
    if (threadIdx.x == 0) {
        float d = s_dot[0] + s_dot[1] + s_dot[2] + s_dot[3];
        float na = s_aa[0] + s_aa[1] + s_aa[2] + s_aa[3];
        float nb = s_bb[0] + s_bb[1] + s_bb[2] + s_bb[3];
        float cosv = d * rsqrtf(na * nb);
        atomicAdd(out, (1.0f - cosv) * (1.0f / (float)ROWS));
    }
}

extern "C" void kernel_launch(void* const* d_in, const int* in_sizes, int n_in,
                              void* d_out, int out_size, void* d_ws, size_t ws_size,
                              hipStream_t stream) {
    const float4* cxr = (const float4*)d_in[0];
    const float4* ehr = (const float4*)d_in[1];
    float* out = (float*)d_out;

    // d_out is re-poisoned to 0xAA before every launch; zero it (stream-ordered,
    // graph-capture safe).
    hipMemsetAsync(d_out, 0, sizeof(float), stream);

    cosine_loss_kernel<<<ROWS, BLOCK, 0, stream>>>(cxr, ehr, out);
}

// Round 2
// 277.163 us; speedup vs baseline: 1.4419x; 1.4419x over previous
//
#include <hip/hip_runtime.h>
#include <hip/hip_bf16.h>

// CosineLoss: out = mean_i( 1 - dot(a_i,b_i) / (||a_i||*||b_i||) )
// inputs: d_in[0]=cxr (N,D) f32, d_in[1]=ehr (N,D) f32; N=16384, D=2048.
// Memory-bound: 268 MB read (LLC absorbs ~half -> ~134 MB HBM observed).
//
// R1 lesson: block-per-row with 4 loads/thread + 16384 same-address atomics
// was latency/atomic-bound at 607 GB/s. Now: wave-per-row (16 float4 loads
// in flight per lane), per-block partial to d_ws, separate reduce kernel.

#define ROWS 16384
#define COLS 2048
#define BLOCK 256
#define WAVES_PER_BLOCK 4              // 4 rows per block
#define GRID (ROWS / WAVES_PER_BLOCK)  // 4096 blocks
#define NVEC (COLS / 4)                // 512 float4 per row
#define VPL (NVEC / 64)                // 8 float4 per lane per array

__global__ __launch_bounds__(BLOCK) void cosine_partial_kernel(
    const float4* __restrict__ cxr,
    const float4* __restrict__ ehr,
    float* __restrict__ partial) {
    const int wave = threadIdx.x >> 6;
    const int lane = threadIdx.x & 63;
    const int row  = blockIdx.x * WAVES_PER_BLOCK + wave;

    const float4* __restrict__ a = cxr + (size_t)row * NVEC;
    const float4* __restrict__ b = ehr + (size_t)row * NVEC;

    // Load everything first: 16 independent 16B loads in flight per lane.
    float4 x[VPL], y[VPL];
    #pragma unroll
    for (int k = 0; k < VPL; ++k) x[k] = a[lane + 64 * k];
    #pragma unroll
    for (int k = 0; k < VPL; ++k) y[k] = b[lane + 64 * k];

    float dot = 0.f, aa = 0.f, bb = 0.f;
    #pragma unroll
    for (int k = 0; k < VPL; ++k) {
        dot += x[k].x * y[k].x + x[k].y * y[k].y + x[k].z * y[k].z + x[k].w * y[k].w;
        aa  += x[k].x * x[k].x + x[k].y * x[k].y + x[k].z * x[k].z + x[k].w * x[k].w;
        bb  += y[k].x * y[k].x + y[k].y * y[k].y + y[k].z * y[k].z + y[k].w * y[k].w;
    }

    // wave64 reduction
    #pragma unroll
    for (int off = 32; off > 0; off >>= 1) {
        dot += __shfl_down(dot, off, 64);
        aa  += __shfl_down(aa,  off, 64);
        bb  += __shfl_down(bb,  off, 64);
    }

    __shared__ float s_loss[WAVES_PER_BLOCK];
    if (lane == 0) {
        s_loss[wave] = 1.0f - dot * rsqrtf(aa * bb);
    }
    __syncthreads();
    if (threadIdx.x == 0) {
        partial[blockIdx.x] = s_loss[0] + s_loss[1] + s_loss[2] + s_loss[3];
    }
}

__global__ __launch_bounds__(BLOCK) void cosine_reduce_kernel(
    const float* __restrict__ partial,
    float* __restrict__ out) {
    float s = 0.f;
    for (int i = threadIdx.x; i < GRID; i += BLOCK) s += partial[i];
    #pragma unroll
    for (int off = 32; off > 0; off >>= 1) s += __shfl_down(s, off, 64);

    __shared__ float s_sum[BLOCK / 64];
    const int wave = threadIdx.x >> 6;
    const int lane = threadIdx.x & 63;
    if (lane == 0) s_sum[wave] = s;
    __syncthreads();
    if (threadIdx.x == 0) {
        out[0] = (s_sum[0] + s_sum[1] + s_sum[2] + s_sum[3]) * (1.0f / (float)ROWS);
    }
}

extern "C" void kernel_launch(void* const* d_in, const int* in_sizes, int n_in,
                              void* d_out, int out_size, void* d_ws, size_t ws_size,
                              hipStream_t stream) {
    const float4* cxr = (const float4*)d_in[0];
    const float4* ehr = (const float4*)d_in[1];
    float* out     = (float*)d_out;
    float* partial = (float*)d_ws;  // 4096 floats = 16 KB, fully overwritten

    cosine_partial_kernel<<<GRID, BLOCK, 0, stream>>>(cxr, ehr, partial);
    cosine_reduce_kernel<<<1, BLOCK, 0, stream>>>(partial, out);
}